// Round 8
// baseline (175.071 us; speedup 1.0000x reference)
//
#include <hip/hip_runtime.h>

// Problem constants
#define BB   4
#define SS   2048
#define HH   8
#define CC   32
#define CIN  256

typedef unsigned short u16;
typedef unsigned int   u32;
typedef u16 u16x4 __attribute__((ext_vector_type(4)));
typedef u16 u16x8 __attribute__((ext_vector_type(8)));
typedef u32 u32x2 __attribute__((ext_vector_type(2)));
typedef short s16x4 __attribute__((ext_vector_type(4)));
typedef __bf16 bf16x8 __attribute__((ext_vector_type(8)));
typedef float f32x4 __attribute__((ext_vector_type(4)));

__device__ __forceinline__ f32x4 mfma16(u16x8 a, u16x8 b, f32x4 c) {
  return __builtin_amdgcn_mfma_f32_16x16x32_bf16(
      __builtin_bit_cast(bf16x8, a), __builtin_bit_cast(bf16x8, b), c, 0, 0, 0);
}

// 16x16x16 bf16 MFMA: A/B = 4 bf16 (2 VGPRs).  A: row=l15, k=lg*4+e.
// B: col=l15, k=lg*4+e.  D: col=l15, row=lg*4+r (same as 16x16x32).
__device__ __forceinline__ f32x4 mfma16k(u32x2 a, u32x2 b, f32x4 c) {
#if __has_builtin(__builtin_amdgcn_mfma_f32_16x16x16bf16_1k)
  return __builtin_amdgcn_mfma_f32_16x16x16bf16_1k(
      __builtin_bit_cast(s16x4, a), __builtin_bit_cast(s16x4, b), c, 0, 0, 0);
#else
  f32x4 d = c;
  asm volatile("v_mfma_f32_16x16x16_bf16 %0, %1, %2, %0"
               : "+v"(d) : "v"(a), "v"(b));
  return d;
#endif
}

// packed fp32x2 -> bf16x2 (low word = first operand)
__device__ __forceinline__ u32 cvtpk(float a, float b) {
  u32 r;
  asm("v_cvt_pk_bf16_f32 %0, %1, %2" : "=v"(r) : "v"(a), "v"(b));
  return r;
}

__device__ __forceinline__ f32x4 ldf4(const float* p) {
  float4 v = *(const float4*)p;
  f32x4 z = {v.x, v.y, v.z, v.w};
  return z;
}

// round-to-nearest-even fp32 -> bf16 (finite inputs only)
__device__ __forceinline__ u16 bf16_rne(float x) {
  unsigned u = __float_as_uint(x);
  u += 0x7FFFu + ((u >> 16) & 1u);
  return (u16)(u >> 16);
}
// split fp32 into bf16 hi + bf16 lo (x ~= hi + lo, ~16-bit mantissa total)
__device__ __forceinline__ void cvt_pair(float x, u16 &hi, u16 &lo) {
  hi = bf16_rne(x);
  lo = bf16_rne(x - __uint_as_float(((unsigned)hi) << 16));
}

// ------------------------------------------------------------------
// K0a: x [8192,256] f32 -> xh, xl bf16
// ------------------------------------------------------------------
__global__ void k_cvt_x(const float* __restrict__ x,
                        u16* __restrict__ xh, u16* __restrict__ xl) {
  int i = (blockIdx.x * 256 + threadIdx.x) * 4;
  float4 v = *(const float4*)(x + i);
  u16x4 h, l;
  u16 th, tl;
  cvt_pair(v.x, th, tl); h[0] = th; l[0] = tl;
  cvt_pair(v.y, th, tl); h[1] = th; l[1] = tl;
  cvt_pair(v.z, th, tl); h[2] = th; l[2] = tl;
  cvt_pair(v.w, th, tl); h[3] = th; l[3] = tl;
  *(u16x4*)(xh + i) = h;
  *(u16x4*)(xl + i) = l;
}

// ------------------------------------------------------------------
// K0b: weights -> transposed bf16 pairs via LDS tile transpose (coalesced).
// ------------------------------------------------------------------
__global__ void k_cvt_w(const float* __restrict__ Wq, const float* __restrict__ Wk,
                        const float* __restrict__ Wv, const float* __restrict__ Wg,
                        const float* __restrict__ Wo,
                        u16* __restrict__ wt4h, u16* __restrict__ wt4l,
                        u16* __restrict__ woth, u16* __restrict__ wotl) {
  __shared__ float tile[64][65];
  const int mat = blockIdx.x / 16, tt = blockIdx.x % 16;
  const int m0 = (tt >> 2) * 64, n0 = (tt & 3) * 64;
  const float* W = (mat == 0) ? Wq : (mat == 1) ? Wk : (mat == 2) ? Wv
                 : (mat == 3) ? Wg : Wo;
  const int tr = threadIdx.x >> 6;   // 0..3
  const int tc = threadIdx.x & 63;   // 0..63
#pragma unroll
  for (int i = 0; i < 16; ++i) {
    int row = i * 4 + tr;
    tile[row][tc] = W[(m0 + row) * 256 + n0 + tc];
  }
  __syncthreads();
  u16* dh = (mat < 4) ? wt4h : woth;
  u16* dl = (mat < 4) ? wt4l : wotl;
  const int nbase = (mat < 4) ? mat * 256 : 0;
#pragma unroll
  for (int i = 0; i < 16; ++i) {
    int row = i * 4 + tr;               // n-dim
    u16 hi, lo; cvt_pair(tile[tc][row], hi, lo);
    dh[(nbase + n0 + row) * 256 + m0 + tc] = hi;
    dl[(nbase + n0 + row) * 256 + m0 + tc] = lo;
  }
}

// ------------------------------------------------------------------
// Kernel A: fused QKVG projection GEMM.  y = x @ [Wq|Wk|Wv|Wg]
// ------------------------------------------------------------------
__global__ __launch_bounds__(256, 2) void k_proj(
    const u16* __restrict__ xh, const u16* __restrict__ xl,
    const u16* __restrict__ wt4h, const u16* __restrict__ wt4l,
    const float* __restrict__ bg,
    u16* __restrict__ qh, u16* __restrict__ ql,
    u16* __restrict__ kh, u16* __restrict__ kl,
    u16* __restrict__ vth, u16* __restrict__ vtl,
    float* __restrict__ g) {
  const int m0 = blockIdx.x * 128;      // 64 blocks
  const int n0 = blockIdx.y * 128;      // 8 blocks
  const int wave = threadIdx.x >> 6;
  const int lane = threadIdx.x & 63;
  const int wm = (wave >> 1) * 64, wn = (wave & 1) * 64;
  const int l15 = lane & 15, lg = lane >> 4;

  f32x4 acc[4][4] = {};
  for (int ks = 0; ks < 8; ++ks) {
    u16x8 a_h[4], a_l[4], b_h[4], b_l[4];
#pragma unroll
    for (int mt = 0; mt < 4; ++mt) {
      int base = (m0 + wm + mt * 16 + l15) * 256 + ks * 32 + lg * 8;
      a_h[mt] = *(const u16x8*)(xh + base);
      a_l[mt] = *(const u16x8*)(xl + base);
    }
#pragma unroll
    for (int nt = 0; nt < 4; ++nt) {
      int base = (n0 + wn + nt * 16 + l15) * 256 + ks * 32 + lg * 8;
      b_h[nt] = *(const u16x8*)(wt4h + base);
      b_l[nt] = *(const u16x8*)(wt4l + base);
    }
#pragma unroll
    for (int mt = 0; mt < 4; ++mt)
#pragma unroll
      for (int nt = 0; nt < 4; ++nt) {
        acc[mt][nt] = mfma16(a_h[mt], b_h[nt], acc[mt][nt]);
        acc[mt][nt] = mfma16(a_h[mt], b_l[nt], acc[mt][nt]);
        acc[mt][nt] = mfma16(a_l[mt], b_h[nt], acc[mt][nt]);
      }
  }

  const float qscale = 0.17677669529663687f;  // 1/sqrt(32)
#pragma unroll
  for (int mt = 0; mt < 4; ++mt)
#pragma unroll
    for (int nt = 0; nt < 4; ++nt) {
      const int rowb = m0 + wm + mt * 16 + lg * 4;  // + r (4 consecutive rows)
      const int col  = n0 + wn + nt * 16 + l15;
      const int bb = rowb >> 11, s = rowb & 2047;
      const int mid = col >> 8, d = col & 255;
      const int hh = d >> 5, c = d & 31;
      if (mid == 3) {
#pragma unroll
        for (int r = 0; r < 4; ++r) {
          float gv = 1.0f / (1.0f + __expf(-(acc[mt][nt][r] + bg[d])));
          g[(rowb + r) * 256 + d] = gv;
        }
      } else if (mid == 2) {
        u16x4 vh4, vl4;
#pragma unroll
        for (int r = 0; r < 4; ++r) {
          u16 th, tl; cvt_pair(acc[mt][nt][r], th, tl);
          vh4[r] = th; vl4[r] = tl;
        }
        size_t idx = ((size_t)(bb * HH + hh) * CC + c) * SS + s;
        *(u16x4*)(vth + idx) = vh4;
        *(u16x4*)(vtl + idx) = vl4;
      } else {
#pragma unroll
        for (int r = 0; r < 4; ++r) {
          float val = acc[mt][nt][r];
          if (mid == 0) val *= qscale;
          u16 th, tl; cvt_pair(val, th, tl);
          size_t idx = ((size_t)(bb * HH + hh) * SS + s + r) * CC + c;
          if (mid == 0) { qh[idx] = th; ql[idx] = tl; }
          else          { kh[idx] = th; kl[idx] = tl; }
        }
      }
    }
}

// ------------------------------------------------------------------
// Kernel B: attention.  1024 blocks x 256 threads (4 waves x 32 q-rows).
// Block = (h, b, j-half, q-chunk 128).  LDS = KV dbuf only (38,912 B ->
// 4 blocks/CU).  PV uses 16x16x16 MFMA whose A-layout (k=lg*4+e) matches
// the QK output exactly -> NO P LDS round-trip.  Swapped QK, bias C-init.
// Writes unnormalized numer + denom per j-half; k_out combines.
// ------------------------------------------------------------------
__global__ __launch_bounds__(256, 4) void k_attn(
    const u16* __restrict__ qh, const u16* __restrict__ ql,
    const u16* __restrict__ kh, const u16* __restrict__ kl,
    const u16* __restrict__ vth, const u16* __restrict__ vtl,
    const float* __restrict__ bias,
    float* __restrict__ n0, float* __restrict__ n1,
    float* __restrict__ d0, float* __restrict__ d1) {
  // u16 layout per KV buffer (9728 u16 = 19456 B):
  //   KH [64][40] @0, KL @2560, VH [32][72] @5120, VL @7424
  __shared__ __align__(16) u32 lds32[9728];   // 38,912 B
  u16* ldsu = (u16*)lds32;

  const int idx = blockIdx.x;            // 1024
  const int h   = idx & 7;               // head -> XCD pinning
  const int b   = (idx >> 3) & 3;        // b-blocks adjacent -> bias L2 share
  const int jh  = (idx >> 5) & 1;
  const int q0  = (idx >> 6) * 128;      // 16 q-chunks
  const int w    = threadIdx.x >> 6;     // 0..3
  const int lane = threadIdx.x & 63;
  const int l15 = lane & 15, lg = lane >> 4;
  const int bh = b * HH + h;
  const int t = threadIdx.x;
  const int jbase = jh * 1024;

  float* nb = jh ? n1 : n0;
  float* db = jh ? d1 : d0;

  // cooperative stage addressing (256 threads, u16x8 = 16B each)
  const int kj = t >> 2, kc = (t & 3) * 8;   // K: [64 j][32 c]
  const int vc = t >> 3, vj = (t & 7) * 8;   // V: [32 c][64 j]
  const size_t gk = ((size_t)bh * SS + jbase + kj) * CC + kc;
  const size_t gv = ((size_t)bh * CC + vc) * SS + jbase + vj;

  // Q fragments (B operand of 16x16x32: col=q=l15, k=c=lg*8+e)
  u16x8 qfh[2], qfl[2];
#pragma unroll
  for (int qt = 0; qt < 2; ++qt) {
    int base = (bh * SS + q0 + w * 32 + qt * 16 + l15) * CC + lg * 8;
    qfh[qt] = *(const u16x8*)(qh + base);
    qfl[qt] = *(const u16x8*)(ql + base);
  }

  const float* biasQ[2];
#pragma unroll
  for (int qt = 0; qt < 2; ++qt)
    biasQ[qt] = bias + (size_t)h * SS * SS
              + (size_t)(q0 + w * 32 + qt * 16 + l15) * SS + jbase + lg * 4;

  f32x4 oacc[2][2] = {};   // [qt][ct]
  float rs[2] = {0.0f, 0.0f};

  // ---- prologue: stage tile 0 ----
  {
    u16x8 a = *(const u16x8*)(kh + gk);
    u16x8 c = *(const u16x8*)(kl + gk);
    u16x8 e = *(const u16x8*)(vth + gv);
    u16x8 f = *(const u16x8*)(vtl + gv);
    *(u16x8*)(ldsu + kj * 40 + kc) = a;
    *(u16x8*)(ldsu + 2560 + kj * 40 + kc) = c;
    *(u16x8*)(ldsu + 5120 + vc * 72 + vj) = e;
    *(u16x8*)(ldsu + 7424 + vc * 72 + vj) = f;
  }
  __syncthreads();

#pragma unroll 1
  for (int jt = 0; jt < 16; ++jt) {
    const int cur = jt & 1;
    const u16* lk = ldsu + cur * 9728;

    // --- bias as MFMA C-init: sacc[qt][at][r] = bias[q=l15][j0+at*16+lg*4+r]
    f32x4 sacc[2][4];
#pragma unroll
    for (int qt = 0; qt < 2; ++qt)
#pragma unroll
      for (int at = 0; at < 4; ++at)
        sacc[qt][at] = ldf4(biasQ[qt] + jt * 64 + at * 16);

    // --- swapped QK^T (16x16x32), K frags from LDS: D[j][q] ---
#pragma unroll
    for (int at = 0; at < 4; ++at) {
      int kb = (at * 16 + l15) * 40 + lg * 8;
      u16x8 kah = *(const u16x8*)(lk + kb);
      u16x8 kal = *(const u16x8*)(lk + 2560 + kb);
#pragma unroll
      for (int qt = 0; qt < 2; ++qt) {
        sacc[qt][at] = mfma16(kah, qfh[qt], sacc[qt][at]);
        sacc[qt][at] = mfma16(kah, qfl[qt], sacc[qt][at]);
        sacc[qt][at] = mfma16(kal, qfh[qt], sacc[qt][at]);
      }
    }

    // --- issue next tile's global loads (hide under softmax+PV) ---
    u16x8 skh, skl, svh, svl;
    if (jt < 15) {
      const size_t ko = (size_t)(jt + 1) * 64 * CC;
      const size_t vo = (size_t)(jt + 1) * 64;
      skh = *(const u16x8*)(kh + gk + ko);
      skl = *(const u16x8*)(kl + gk + ko);
      svh = *(const u16x8*)(vth + gv + vo);
      svl = *(const u16x8*)(vtl + gv + vo);
    }

    // --- per at: exp + pack (= PV A-frag directly) + PV MFMAs ---
#pragma unroll
    for (int at = 0; at < 4; ++at) {
      u32x2 ph[2], pl[2];
#pragma unroll
      for (int qt = 0; qt < 2; ++qt) {
        float p0 = __expf(sacc[qt][at][0]);
        float p1 = __expf(sacc[qt][at][1]);
        float p2 = __expf(sacc[qt][at][2]);
        float p3 = __expf(sacc[qt][at][3]);
        rs[qt] += (p0 + p1) + (p2 + p3);
        u32 hA = cvtpk(p0, p1), hB = cvtpk(p2, p3);
        float f0 = __uint_as_float(hA << 16);
        float f1 = __uint_as_float(hA & 0xffff0000u);
        float f2 = __uint_as_float(hB << 16);
        float f3 = __uint_as_float(hB & 0xffff0000u);
        u32 lA = cvtpk(p0 - f0, p1 - f1);
        u32 lB = cvtpk(p2 - f2, p3 - f3);
        ph[qt][0] = hA; ph[qt][1] = hB;
        pl[qt][0] = lA; pl[qt][1] = lB;
      }
#pragma unroll
      for (int ct = 0; ct < 2; ++ct) {
        int vb = 5120 + (ct * 16 + l15) * 72 + at * 16 + lg * 4;
        u32x2 vfh = *(const u32x2*)(lk + vb);
        u32x2 vfl = *(const u32x2*)(lk + vb + 2304);
#pragma unroll
        for (int qt = 0; qt < 2; ++qt) {
          oacc[qt][ct] = mfma16k(ph[qt], vfh, oacc[qt][ct]);
          oacc[qt][ct] = mfma16k(ph[qt], vfl, oacc[qt][ct]);
          oacc[qt][ct] = mfma16k(pl[qt], vfh, oacc[qt][ct]);
        }
      }
    }

    // --- write next tile into the other buffer ---
    if (jt < 15) {
      u16* ln = ldsu + (cur ^ 1) * 9728;
      *(u16x8*)(ln + kj * 40 + kc) = skh;
      *(u16x8*)(ln + 2560 + kj * 40 + kc) = skl;
      *(u16x8*)(ln + 5120 + vc * 72 + vj) = svh;
      *(u16x8*)(ln + 7424 + vc * 72 + vj) = svl;
    }
    __syncthreads();
  }

  // full rowsum for q = l15 (sum over lg groups)
#pragma unroll
  for (int qt = 0; qt < 2; ++qt) {
    rs[qt] += __shfl_xor(rs[qt], 16, 64);
    rs[qt] += __shfl_xor(rs[qt], 32, 64);
  }
  // write denom (once per q-row) and unnormalized numer [B,S,H,C]
#pragma unroll
  for (int qt = 0; qt < 2; ++qt) {
    if (lg == 0)
      db[(size_t)(b * SS + q0 + w * 32 + qt * 16 + l15) * HH + h] = rs[qt];
#pragma unroll
    for (int ct = 0; ct < 2; ++ct)
#pragma unroll
      for (int r = 0; r < 4; ++r) {
        int qg = q0 + w * 32 + qt * 16 + lg * 4 + r;
        nb[((size_t)(b * SS + qg) * HH + h) * CC + ct * 16 + l15] =
            oacc[qt][ct][r];
      }
  }
}

// ------------------------------------------------------------------
// Kernel C: out = (g .* (n0+n1)/(d0+d1)) @ Wo + bo.  M=8192, N=256, K=256.
// ------------------------------------------------------------------
__global__ __launch_bounds__(256, 2) void k_out(
    const float* __restrict__ n0, const float* __restrict__ n1,
    const float* __restrict__ d0, const float* __restrict__ d1,
    const float* __restrict__ g,
    const u16* __restrict__ woth, const u16* __restrict__ wotl,
    const float* __restrict__ bo, float* __restrict__ out) {
  const int m0 = blockIdx.x * 32;    // 256 blocks
  const int nn0 = blockIdx.y * 128;  // 2 blocks
  const int wave = threadIdx.x >> 6;
  const int lane = threadIdx.x & 63;
  const int wn = wave * 32;
  const int l15 = lane & 15, lg = lane >> 4;

  f32x4 acc[2][2] = {};
  for (int ks = 0; ks < 8; ++ks) {
    u16x8 a_h[2], a_l[2], b_h[2], b_l[2];
#pragma unroll
    for (int mt = 0; mt < 2; ++mt) {
      int row = m0 + mt * 16 + l15;
      int base = row * 256 + ks * 32 + lg * 8;
      float inv = 1.0f / (d0[row * 8 + ks] + d1[row * 8 + ks]);
      float4 a0 = *(const float4*)(n0 + base);
      float4 a1 = *(const float4*)(n0 + base + 4);
      float4 c0 = *(const float4*)(n1 + base);
      float4 c1 = *(const float4*)(n1 + base + 4);
      float4 g0 = *(const float4*)(g + base);
      float4 g1 = *(const float4*)(g + base + 4);
      float pr[8] = {(a0.x + c0.x) * inv * g0.x, (a0.y + c0.y) * inv * g0.y,
                     (a0.z + c0.z) * inv * g0.z, (a0.w + c0.w) * inv * g0.w,
                     (a1.x + c1.x) * inv * g1.x, (a1.y + c1.y) * inv * g1.y,
                     (a1.z + c1.z) * inv * g1.z, (a1.w + c1.w) * inv * g1.w};
      union { u16 s[8]; u16x8 v; } uh, ul;
#pragma unroll
      for (int e = 0; e < 8; ++e) { u16 th, tl; cvt_pair(pr[e], th, tl); uh.s[e] = th; ul.s[e] = tl; }
      a_h[mt] = uh.v; a_l[mt] = ul.v;
    }
#pragma unroll
    for (int nt = 0; nt < 2; ++nt) {
      int base = (nn0 + wn + nt * 16 + l15) * 256 + ks * 32 + lg * 8;
      b_h[nt] = *(const u16x8*)(woth + base);
      b_l[nt] = *(const u16x8*)(wotl + base);
    }
#pragma unroll
    for (int mt = 0; mt < 2; ++mt)
#pragma unroll
      for (int nt = 0; nt < 2; ++nt) {
        acc[mt][nt] = mfma16(a_h[mt], b_h[nt], acc[mt][nt]);
        acc[mt][nt] = mfma16(a_h[mt], b_l[nt], acc[mt][nt]);
        acc[mt][nt] = mfma16(a_l[mt], b_h[nt], acc[mt][nt]);
      }
  }
#pragma unroll
  for (int mt = 0; mt < 2; ++mt)
#pragma unroll
    for (int nt = 0; nt < 2; ++nt)
#pragma unroll
      for (int r = 0; r < 4; ++r) {
        int row = m0 + mt * 16 + lg * 4 + r;
        int col = nn0 + wn + nt * 16 + l15;
        out[row * 256 + col] = acc[mt][nt][r] + bo[col];
      }
}

// ------------------------------------------------------------------
extern "C" void kernel_launch(void* const* d_in, const int* in_sizes, int n_in,
                              void* d_out, int out_size, void* d_ws, size_t ws_size,
                              hipStream_t stream) {
  const float* x    = (const float*)d_in[0];
  const float* bias = (const float*)d_in[1];
  const float* Wq   = (const float*)d_in[2];
  const float* Wk   = (const float*)d_in[3];
  const float* Wv   = (const float*)d_in[4];
  const float* Wg   = (const float*)d_in[5];
  const float* bg   = (const float*)d_in[6];
  const float* Wo   = (const float*)d_in[7];
  const float* bo   = (const float*)d_in[8];
  float* out = (float*)d_out;

  char* p = (char*)d_ws;
  size_t used = 0;
  auto alloc = [&](size_t bytes) -> void* {
    void* r = p + used;
    used += (bytes + 255) & ~(size_t)255;
    return r;
  };
  const size_t NTOK = (size_t)BB * SS * CIN;   // 2,097,152
  u16* xh   = (u16*)alloc(NTOK * 2);
  u16* xl   = (u16*)alloc(NTOK * 2);
  u16* wt4h = (u16*)alloc(1024 * 256 * 2);
  u16* wt4l = (u16*)alloc(1024 * 256 * 2);
  u16* woth = (u16*)alloc(256 * 256 * 2);
  u16* wotl = (u16*)alloc(256 * 256 * 2);
  u16* qh   = (u16*)alloc(NTOK * 2);
  u16* ql   = (u16*)alloc(NTOK * 2);
  u16* kh   = (u16*)alloc(NTOK * 2);
  u16* kl   = (u16*)alloc(NTOK * 2);
  u16* vth  = (u16*)alloc(NTOK * 2);
  u16* vtl  = (u16*)alloc(NTOK * 2);
  float* gbuf = (float*)alloc(NTOK * 4);
  float* nb0  = (float*)alloc(NTOK * 4);
  float* nb1  = (float*)alloc(NTOK * 4);
  float* db0  = (float*)alloc((size_t)BB * SS * HH * 4);
  float* db1  = (float*)alloc((size_t)BB * SS * HH * 4);
  if (used > ws_size) return;

  k_cvt_x<<<dim3(2048), dim3(256), 0, stream>>>(x, xh, xl);
  k_cvt_w<<<dim3(80), dim3(256), 0, stream>>>(Wq, Wk, Wv, Wg, Wo, wt4h, wt4l, woth, wotl);
  k_proj<<<dim3(64, 8), dim3(256), 0, stream>>>(xh, xl, wt4h, wt4l, bg,
                                                qh, ql, kh, kl, vth, vtl, gbuf);
  k_attn<<<dim3(1024), dim3(256), 0, stream>>>(qh, ql, kh, kl, vth, vtl, bias,
                                               nb0, nb1, db0, db1);
  k_out<<<dim3(256, 2), dim3(256), 0, stream>>>(nb0, nb1, db0, db1, gbuf,
                                                woth, wotl, bo, out);
}

// Round 13
// 166.684 us; speedup vs baseline: 1.0503x; 1.0503x over previous
//
#include <hip/hip_runtime.h>

// Problem constants
#define BB   4
#define SS   2048
#define HH   8
#define CC   32
#define CIN  256

typedef unsigned short u16;
typedef unsigned int   u32;
typedef u16 u16x4 __attribute__((ext_vector_type(4)));
typedef u16 u16x8 __attribute__((ext_vector_type(8)));
typedef __bf16 bf16x8 __attribute__((ext_vector_type(8)));
typedef float f32x4 __attribute__((ext_vector_type(4)));

// PINNED LESSON (R9-R12): do NOT reintroduce the 16x16x16 reg-PV (mfma16k)
// in combination with the bias register-prefetch — schedule/regalloc-
// dependent corruption (2e33/NaN).  This kernel uses only the verified
// 16x16x32 builtin MFMA path (R7, PASS @ 164 us).

__device__ __forceinline__ f32x4 mfma16(u16x8 a, u16x8 b, f32x4 c) {
  return __builtin_amdgcn_mfma_f32_16x16x32_bf16(
      __builtin_bit_cast(bf16x8, a), __builtin_bit_cast(bf16x8, b), c, 0, 0, 0);
}

// packed fp32x2 -> bf16x2 (low word = first operand)
__device__ __forceinline__ u32 cvtpk(float a, float b) {
  u32 r;
  asm("v_cvt_pk_bf16_f32 %0, %1, %2" : "=v"(r) : "v"(a), "v"(b));
  return r;
}

__device__ __forceinline__ f32x4 ldf4(const float* p) {
  float4 v = *(const float4*)p;
  f32x4 z = {v.x, v.y, v.z, v.w};
  return z;
}

// round-to-nearest-even fp32 -> bf16 (finite inputs only)
__device__ __forceinline__ u16 bf16_rne(float x) {
  unsigned u = __float_as_uint(x);
  u += 0x7FFFu + ((u >> 16) & 1u);
  return (u16)(u >> 16);
}
// split fp32 into bf16 hi + bf16 lo (x ~= hi + lo, ~16-bit mantissa total)
__device__ __forceinline__ void cvt_pair(float x, u16 &hi, u16 &lo) {
  hi = bf16_rne(x);
  lo = bf16_rne(x - __uint_as_float(((unsigned)hi) << 16));
}

// ------------------------------------------------------------------
// K0a: x [8192,256] f32 -> xh, xl bf16
// ------------------------------------------------------------------
__global__ void k_cvt_x(const float* __restrict__ x,
                        u16* __restrict__ xh, u16* __restrict__ xl) {
  int i = (blockIdx.x * 256 + threadIdx.x) * 4;
  float4 v = *(const float4*)(x + i);
  u16x4 h, l;
  u16 th, tl;
  cvt_pair(v.x, th, tl); h[0] = th; l[0] = tl;
  cvt_pair(v.y, th, tl); h[1] = th; l[1] = tl;
  cvt_pair(v.z, th, tl); h[2] = th; l[2] = tl;
  cvt_pair(v.w, th, tl); h[3] = th; l[3] = tl;
  *(u16x4*)(xh + i) = h;
  *(u16x4*)(xl + i) = l;
}

// ------------------------------------------------------------------
// K0b: weights -> transposed bf16 pairs via LDS tile transpose (coalesced).
// ------------------------------------------------------------------
__global__ void k_cvt_w(const float* __restrict__ Wq, const float* __restrict__ Wk,
                        const float* __restrict__ Wv, const float* __restrict__ Wg,
                        const float* __restrict__ Wo,
                        u16* __restrict__ wt4h, u16* __restrict__ wt4l,
                        u16* __restrict__ woth, u16* __restrict__ wotl) {
  __shared__ float tile[64][65];
  const int mat = blockIdx.x / 16, tt = blockIdx.x % 16;
  const int m0 = (tt >> 2) * 64, n0 = (tt & 3) * 64;
  const float* W = (mat == 0) ? Wq : (mat == 1) ? Wk : (mat == 2) ? Wv
                 : (mat == 3) ? Wg : Wo;
  const int tr = threadIdx.x >> 6;   // 0..3
  const int tc = threadIdx.x & 63;   // 0..63
#pragma unroll
  for (int i = 0; i < 16; ++i) {
    int row = i * 4 + tr;
    tile[row][tc] = W[(m0 + row) * 256 + n0 + tc];
  }
  __syncthreads();
  u16* dh = (mat < 4) ? wt4h : woth;
  u16* dl = (mat < 4) ? wt4l : wotl;
  const int nbase = (mat < 4) ? mat * 256 : 0;
#pragma unroll
  for (int i = 0; i < 16; ++i) {
    int row = i * 4 + tr;               // n-dim
    u16 hi, lo; cvt_pair(tile[tc][row], hi, lo);
    dh[(nbase + n0 + row) * 256 + m0 + tc] = hi;
    dl[(nbase + n0 + row) * 256 + m0 + tc] = lo;
  }
}

// ------------------------------------------------------------------
// Kernel A: fused QKVG projection GEMM.  y = x @ [Wq|Wk|Wv|Wg]
// ------------------------------------------------------------------
__global__ __launch_bounds__(256, 2) void k_proj(
    const u16* __restrict__ xh, const u16* __restrict__ xl,
    const u16* __restrict__ wt4h, const u16* __restrict__ wt4l,
    const float* __restrict__ bg,
    u16* __restrict__ qh, u16* __restrict__ ql,
    u16* __restrict__ kh, u16* __restrict__ kl,
    u16* __restrict__ vth, u16* __restrict__ vtl,
    float* __restrict__ g) {
  const int m0 = blockIdx.x * 128;      // 64 blocks
  const int n0 = blockIdx.y * 128;      // 8 blocks
  const int wave = threadIdx.x >> 6;
  const int lane = threadIdx.x & 63;
  const int wm = (wave >> 1) * 64, wn = (wave & 1) * 64;
  const int l15 = lane & 15, lg = lane >> 4;

  f32x4 acc[4][4] = {};
  for (int ks = 0; ks < 8; ++ks) {
    u16x8 a_h[4], a_l[4], b_h[4], b_l[4];
#pragma unroll
    for (int mt = 0; mt < 4; ++mt) {
      int base = (m0 + wm + mt * 16 + l15) * 256 + ks * 32 + lg * 8;
      a_h[mt] = *(const u16x8*)(xh + base);
      a_l[mt] = *(const u16x8*)(xl + base);
    }
#pragma unroll
    for (int nt = 0; nt < 4; ++nt) {
      int base = (n0 + wn + nt * 16 + l15) * 256 + ks * 32 + lg * 8;
      b_h[nt] = *(const u16x8*)(wt4h + base);
      b_l[nt] = *(const u16x8*)(wt4l + base);
    }
#pragma unroll
    for (int mt = 0; mt < 4; ++mt)
#pragma unroll
      for (int nt = 0; nt < 4; ++nt) {
        acc[mt][nt] = mfma16(a_h[mt], b_h[nt], acc[mt][nt]);
        acc[mt][nt] = mfma16(a_h[mt], b_l[nt], acc[mt][nt]);
        acc[mt][nt] = mfma16(a_l[mt], b_h[nt], acc[mt][nt]);
      }
  }

  const float qscale = 0.17677669529663687f;  // 1/sqrt(32)
#pragma unroll
  for (int mt = 0; mt < 4; ++mt)
#pragma unroll
    for (int nt = 0; nt < 4; ++nt) {
      const int rowb = m0 + wm + mt * 16 + lg * 4;  // + r (4 consecutive rows)
      const int col  = n0 + wn + nt * 16 + l15;
      const int bb = rowb >> 11, s = rowb & 2047;
      const int mid = col >> 8, d = col & 255;
      const int hh = d >> 5, c = d & 31;
      if (mid == 3) {
#pragma unroll
        for (int r = 0; r < 4; ++r) {
          float gv = 1.0f / (1.0f + __expf(-(acc[mt][nt][r] + bg[d])));
          g[(rowb + r) * 256 + d] = gv;
        }
      } else if (mid == 2) {
        u16x4 vh4, vl4;
#pragma unroll
        for (int r = 0; r < 4; ++r) {
          u16 th, tl; cvt_pair(acc[mt][nt][r], th, tl);
          vh4[r] = th; vl4[r] = tl;
        }
        size_t idx = ((size_t)(bb * HH + hh) * CC + c) * SS + s;
        *(u16x4*)(vth + idx) = vh4;
        *(u16x4*)(vtl + idx) = vl4;
      } else {
#pragma unroll
        for (int r = 0; r < 4; ++r) {
          float val = acc[mt][nt][r];
          if (mid == 0) val *= qscale;
          u16 th, tl; cvt_pair(val, th, tl);
          size_t idx = ((size_t)(bb * HH + hh) * SS + s + r) * CC + c;
          if (mid == 0) { qh[idx] = th; ql[idx] = tl; }
          else          { kh[idx] = th; kl[idx] = tl; }
        }
      }
    }
}

// ------------------------------------------------------------------
// Kernel B: attention.  512 blocks x 256 threads (4 waves x 32 q-rows).
// EXACT R7 structure (PASS @ 113 us): block = (b, h, q-chunk 128),
// 2 blocks/CU (LDS 79,872 B), K/V double-buffered in LDS, bias register-
// prefetched, swapped QK (bias C-init), per-wave P LDS tile [16][36] u32,
// PV via 16x16x32 builtin MFMA (3-term).  ONE change vs R7: s_setprio(1)
// around MFMA clusters — other block on the CU is phase-independent
// (m191-positive regime); pure scheduler hint, zero correctness risk.
// ------------------------------------------------------------------
__global__ __launch_bounds__(256, 2) void k_attn(
    const u16* __restrict__ qh, const u16* __restrict__ ql,
    const u16* __restrict__ kh, const u16* __restrict__ kl,
    const u16* __restrict__ vth, const u16* __restrict__ vtl,
    const float* __restrict__ bias, float* __restrict__ o) {
  // u16 layout per KV buffer (10752 u16 = 21504 B):
  //   KH [64][40] @0, KL @2560, VH [32][88] @5120, VL @7936
  // buffers at u16 0 and 10752; P tiles (u32) at dword 10752:
  //   per wave 2304 u32 = 2 qt x (hi 576 + lo 576), stride-36 rows.
  __shared__ __align__(16) u32 lds32[19968];   // 79,872 B -> 2 blocks/CU
  u16* ldsu = (u16*)lds32;

  const int idx  = blockIdx.x;
  const int h    = idx & 7;            // head -> XCD pinning
  const int b    = (idx >> 3) & 3;
  const int q0   = (idx >> 5) * 128;   // 16 q-chunks
  const int w    = threadIdx.x >> 6;   // 0..3
  const int lane = threadIdx.x & 63;
  const int l15 = lane & 15, lg = lane >> 4;
  const int bh = b * HH + h;
  const int t = threadIdx.x;

  // cooperative stage addressing (256 threads, u16x8 = 16B each)
  const int kj = t >> 2, kc = (t & 3) * 8;   // K: [64 j][32 c]
  const int vc = t >> 3, vj = (t & 7) * 8;   // V: [32 c][64 j]
  const size_t gkbase = ((size_t)bh * SS + kj) * CC + kc;
  const size_t gvbase = ((size_t)bh * CC + vc) * SS + vj;

  // Q fragments (B operand: col=q=l15, k=c), held across the j loop
  u16x8 qfh[2], qfl[2];
#pragma unroll
  for (int qt = 0; qt < 2; ++qt) {
    int base = (bh * SS + q0 + w * 32 + qt * 16 + l15) * CC + lg * 8;
    qfh[qt] = *(const u16x8*)(qh + base);
    qfl[qt] = *(const u16x8*)(ql + base);
  }

  const float* biasQ[2];
#pragma unroll
  for (int qt = 0; qt < 2; ++qt)
    biasQ[qt] = bias + (size_t)h * SS * SS
              + (size_t)(q0 + w * 32 + qt * 16 + l15) * SS + lg * 4;

  u32* pw = lds32 + 10752 + w * 2304;   // per-wave P base (u32)

  f32x4 oacc[2][2] = {};   // [qt][ct]
  float rs[2] = {0.0f, 0.0f};

  // ---- prologue: stage tile 0 + load bias tile 0 ----
  u16x8 skh, skl, svh, svl;
  skh = *(const u16x8*)(kh + gkbase);
  skl = *(const u16x8*)(kl + gkbase);
  svh = *(const u16x8*)(vth + gvbase);
  svl = *(const u16x8*)(vtl + gvbase);
  f32x4 bcur[2][4];
#pragma unroll
  for (int qt = 0; qt < 2; ++qt)
#pragma unroll
    for (int at = 0; at < 4; ++at)
      bcur[qt][at] = ldf4(biasQ[qt] + at * 16);
  *(u16x8*)(ldsu + kj * 40 + kc) = skh;
  *(u16x8*)(ldsu + 2560 + kj * 40 + kc) = skl;
  *(u16x8*)(ldsu + 5120 + vc * 88 + vj) = svh;
  *(u16x8*)(ldsu + 7936 + vc * 88 + vj) = svl;
  __syncthreads();

#pragma unroll 1
  for (int jt = 0; jt < 32; ++jt) {
    const int cur = jt & 1;
    const u16* lk = ldsu + cur * 10752;

    // --- issue next tile's global loads early (hide under compute) ---
    if (jt < 31) {
      const size_t joff = (size_t)(jt + 1) * 64;
      skh = *(const u16x8*)(kh + gkbase + joff * CC);
      skl = *(const u16x8*)(kl + gkbase + joff * CC);
      svh = *(const u16x8*)(vth + gvbase + joff);
      svl = *(const u16x8*)(vtl + gvbase + joff);
    }
    f32x4 bnxt[2][4];
    if (jt < 31) {
#pragma unroll
      for (int qt = 0; qt < 2; ++qt)
#pragma unroll
        for (int at = 0; at < 4; ++at)
          bnxt[qt][at] = ldf4(biasQ[qt] + (jt + 1) * 64 + at * 16);
    }

    // --- K fragments from LDS ---
    u16x8 ka_h[4], ka_l[4];
#pragma unroll
    for (int at = 0; at < 4; ++at) {
      int base = (at * 16 + l15) * 40 + lg * 8;
      ka_h[at] = *(const u16x8*)(lk + base);
      ka_l[at] = *(const u16x8*)(lk + 2560 + base);
    }
    // --- swapped QK^T, bias as C-init: D[j][q] ---
    f32x4 sacc[2][4];
#pragma unroll
    for (int qt = 0; qt < 2; ++qt)
#pragma unroll
      for (int at = 0; at < 4; ++at)
        sacc[qt][at] = bcur[qt][at];
    __builtin_amdgcn_s_setprio(1);
#pragma unroll
    for (int at = 0; at < 4; ++at)
#pragma unroll
      for (int qt = 0; qt < 2; ++qt) {
        sacc[qt][at] = mfma16(ka_h[at], qfh[qt], sacc[qt][at]);
        sacc[qt][at] = mfma16(ka_h[at], qfl[qt], sacc[qt][at]);
        sacc[qt][at] = mfma16(ka_l[at], qfh[qt], sacc[qt][at]);
      }
    __builtin_amdgcn_s_setprio(0);
    // --- exp + rowsum + cvt_pk pack + P LDS write ---
#pragma unroll
    for (int qt = 0; qt < 2; ++qt) {
      u32* pq = pw + qt * 1152;
#pragma unroll
      for (int at = 0; at < 4; ++at) {
        float p0 = __expf(sacc[qt][at][0]);
        float p1 = __expf(sacc[qt][at][1]);
        float p2 = __expf(sacc[qt][at][2]);
        float p3 = __expf(sacc[qt][at][3]);
        rs[qt] += (p0 + p1) + (p2 + p3);
        u32 hA = cvtpk(p0, p1), hB = cvtpk(p2, p3);
        float f0 = __uint_as_float(hA << 16);
        float f1 = __uint_as_float(hA & 0xffff0000u);
        float f2 = __uint_as_float(hB << 16);
        float f3 = __uint_as_float(hB & 0xffff0000u);
        u32 lA = cvtpk(p0 - f0, p1 - f1);
        u32 lB = cvtpk(p2 - f2, p3 - f3);
        int off = l15 * 36 + 8 * at + 2 * lg;
        uint2 Hv; Hv.x = hA; Hv.y = hB;
        uint2 Lv; Lv.x = lA; Lv.y = lB;
        *(uint2*)&pq[off] = Hv;
        *(uint2*)&pq[off + 576] = Lv;
      }
    }
    // --- PV: A = P (row=q=l15, k=j), B = V[c][j] from LDS ---
#pragma unroll
    for (int ks = 0; ks < 2; ++ks) {
      int roff = l15 * 36 + 16 * ks + 4 * lg;
      u16x8 pa_h[2], pa_l[2];
#pragma unroll
      for (int qt = 0; qt < 2; ++qt) {
        pa_h[qt] = *(const u16x8*)(pw + qt * 1152 + roff);
        pa_l[qt] = *(const u16x8*)(pw + qt * 1152 + 576 + roff);
      }
#pragma unroll
      for (int ct = 0; ct < 2; ++ct) {
        int voff = (ct * 16 + l15) * 88 + ks * 32 + lg * 8;
        u16x8 vfh = *(const u16x8*)(lk + 5120 + voff);
        u16x8 vfl = *(const u16x8*)(lk + 7936 + voff);
        __builtin_amdgcn_s_setprio(1);
#pragma unroll
        for (int qt = 0; qt < 2; ++qt) {
          oacc[qt][ct] = mfma16(pa_h[qt], vfh, oacc[qt][ct]);
          oacc[qt][ct] = mfma16(pa_h[qt], vfl, oacc[qt][ct]);
          oacc[qt][ct] = mfma16(pa_l[qt], vfh, oacc[qt][ct]);
        }
        __builtin_amdgcn_s_setprio(0);
      }
    }
    // --- write next tile into the other buffer; rotate bias regs ---
    if (jt < 31) {
      u16* ln = ldsu + (cur ^ 1) * 10752;
      *(u16x8*)(ln + kj * 40 + kc) = skh;
      *(u16x8*)(ln + 2560 + kj * 40 + kc) = skl;
      *(u16x8*)(ln + 5120 + vc * 88 + vj) = svh;
      *(u16x8*)(ln + 7936 + vc * 88 + vj) = svl;
#pragma unroll
      for (int qt = 0; qt < 2; ++qt)
#pragma unroll
        for (int at = 0; at < 4; ++at)
          bcur[qt][at] = bnxt[qt][at];
    }
    __syncthreads();
  }

  // full rowsum for q = l15 (sum over lg groups)
#pragma unroll
  for (int qt = 0; qt < 2; ++qt) {
    rs[qt] += __shfl_xor(rs[qt], 16, 64);
    rs[qt] += __shfl_xor(rs[qt], 32, 64);
  }
  // normalize + write o as [B,S,H,C] fp32 (D: row=q=lg*4+r, col=c=l15)
#pragma unroll
  for (int qt = 0; qt < 2; ++qt) {
    float rsT[4];
#pragma unroll
    for (int r = 0; r < 4; ++r) rsT[r] = __shfl(rs[qt], lg * 4 + r, 64);
#pragma unroll
    for (int ct = 0; ct < 2; ++ct)
#pragma unroll
      for (int r = 0; r < 4; ++r) {
        int qg = q0 + w * 32 + qt * 16 + lg * 4 + r;
        o[((size_t)(b * SS + qg) * HH + h) * CC + ct * 16 + l15] =
            oacc[qt][ct][r] / rsT[r];
      }
  }
}

// ------------------------------------------------------------------
// Kernel C: out = (g .* o) @ Wo + bo.  M=8192, N=256, K=256.
// ------------------------------------------------------------------
__global__ __launch_bounds__(256, 2) void k_out(
    const float* __restrict__ o, const float* __restrict__ g,
    const u16* __restrict__ woth, const u16* __restrict__ wotl,
    const float* __restrict__ bo, float* __restrict__ out) {
  const int m0 = blockIdx.x * 32;    // 256 blocks
  const int n0 = blockIdx.y * 128;   // 2 blocks
  const int wave = threadIdx.x >> 6;
  const int lane = threadIdx.x & 63;
  const int wn = wave * 32;
  const int l15 = lane & 15, lg = lane >> 4;

  f32x4 acc[2][2] = {};
  for (int ks = 0; ks < 8; ++ks) {
    u16x8 a_h[2], a_l[2], b_h[2], b_l[2];
#pragma unroll
    for (int mt = 0; mt < 2; ++mt) {
      int base = (m0 + mt * 16 + l15) * 256 + ks * 32 + lg * 8;
      float4 o0 = *(const float4*)(o + base);
      float4 o1 = *(const float4*)(o + base + 4);
      float4 g0 = *(const float4*)(g + base);
      float4 g1 = *(const float4*)(g + base + 4);
      float pr[8] = {o0.x * g0.x, o0.y * g0.y, o0.z * g0.z, o0.w * g0.w,
                     o1.x * g1.x, o1.y * g1.y, o1.z * g1.z, o1.w * g1.w};
      union { u16 s[8]; u16x8 v; } uh, ul;
#pragma unroll
      for (int e = 0; e < 8; ++e) { u16 th, tl; cvt_pair(pr[e], th, tl); uh.s[e] = th; ul.s[e] = tl; }
      a_h[mt] = uh.v; a_l[mt] = ul.v;
    }
#pragma unroll
    for (int nt = 0; nt < 2; ++nt) {
      int base = (n0 + wn + nt * 16 + l15) * 256 + ks * 32 + lg * 8;
      b_h[nt] = *(const u16x8*)(woth + base);
      b_l[nt] = *(const u16x8*)(wotl + base);
    }
#pragma unroll
    for (int mt = 0; mt < 2; ++mt)
#pragma unroll
      for (int nt = 0; nt < 2; ++nt) {
        acc[mt][nt] = mfma16(a_h[mt], b_h[nt], acc[mt][nt]);
        acc[mt][nt] = mfma16(a_h[mt], b_l[nt], acc[mt][nt]);
        acc[mt][nt] = mfma16(a_l[mt], b_h[nt], acc[mt][nt]);
      }
  }
#pragma unroll
  for (int mt = 0; mt < 2; ++mt)
#pragma unroll
    for (int nt = 0; nt < 2; ++nt)
#pragma unroll
      for (int r = 0; r < 4; ++r) {
        int row = m0 + mt * 16 + lg * 4 + r;
        int col = n0 + wn + nt * 16 + l15;
        out[row * 256 + col] = acc[mt][nt][r] + bo[col];
      }
}

// ------------------------------------------------------------------
extern "C" void kernel_launch(void* const* d_in, const int* in_sizes, int n_in,
                              void* d_out, int out_size, void* d_ws, size_t ws_size,
                              hipStream_t stream) {
  const float* x    = (const float*)d_in[0];
  const float* bias = (const float*)d_in[1];
  const float* Wq   = (const float*)d_in[2];
  const float* Wk   = (const float*)d_in[3];
  const float* Wv   = (const float*)d_in[4];
  const float* Wg   = (const float*)d_in[5];
  const float* bg   = (const float*)d_in[6];
  const float* Wo   = (const float*)d_in[7];
  const float* bo   = (const float*)d_in[8];
  float* out = (float*)d_out;

  char* p = (char*)d_ws;
  size_t used = 0;
  auto alloc = [&](size_t bytes) -> void* {
    void* r = p + used;
    used += (bytes + 255) & ~(size_t)255;
    return r;
  };
  const size_t NTOK = (size_t)BB * SS * CIN;   // 2,097,152
  u16* xh   = (u16*)alloc(NTOK * 2);
  u16* xl   = (u16*)alloc(NTOK * 2);
  u16* wt4h = (u16*)alloc(1024 * 256 * 2);
  u16* wt4l = (u16*)alloc(1024 * 256 * 2);
  u16* woth = (u16*)alloc(256 * 256 * 2);
  u16* wotl = (u16*)alloc(256 * 256 * 2);
  u16* qh   = (u16*)alloc(NTOK * 2);
  u16* ql   = (u16*)alloc(NTOK * 2);
  u16* kh   = (u16*)alloc(NTOK * 2);
  u16* kl   = (u16*)alloc(NTOK * 2);
  u16* vth  = (u16*)alloc(NTOK * 2);
  u16* vtl  = (u16*)alloc(NTOK * 2);
  float* gbuf = (float*)alloc(NTOK * 4);
  float* obuf = (float*)alloc(NTOK * 4);
  if (used > ws_size) return;

  k_cvt_x<<<dim3(2048), dim3(256), 0, stream>>>(x, xh, xl);
  k_cvt_w<<<dim3(80), dim3(256), 0, stream>>>(Wq, Wk, Wv, Wg, Wo, wt4h, wt4l, woth, wotl);
  k_proj<<<dim3(64, 8), dim3(256), 0, stream>>>(xh, xl, wt4h, wt4l, bg,
                                                qh, ql, kh, kl, vth, vtl, gbuf);
  k_attn<<<dim3(512), dim3(256), 0, stream>>>(qh, ql, kh, kl, vth, vtl, bias, obuf);
  k_out<<<dim3(256, 2), dim3(256), 0, stream>>>(obuf, gbuf, woth, wotl, bo, out);
}

// Round 14
// 166.495 us; speedup vs baseline: 1.0515x; 1.0011x over previous
//
#include <hip/hip_runtime.h>

// Problem constants
#define BB   4
#define SS   2048
#define HH   8
#define CC   32
#define CIN  256

typedef unsigned short u16;
typedef unsigned int   u32;
typedef u16 u16x4 __attribute__((ext_vector_type(4)));
typedef u16 u16x8 __attribute__((ext_vector_type(8)));
typedef __bf16 bf16x8 __attribute__((ext_vector_type(8)));
typedef float f32x4 __attribute__((ext_vector_type(4)));

// PINNED LESSON (R9-R12): never combine the 16x16x16 reg-PV (mfma16k) with
// the bias register-prefetch — schedule/regalloc-dependent corruption.
// Only the 16x16x32 builtin MFMA path is used here (R7/R13-verified).

__device__ __forceinline__ f32x4 mfma16(u16x8 a, u16x8 b, f32x4 c) {
  return __builtin_amdgcn_mfma_f32_16x16x32_bf16(
      __builtin_bit_cast(bf16x8, a), __builtin_bit_cast(bf16x8, b), c, 0, 0, 0);
}

// packed fp32x2 -> bf16x2 (low word = first operand)
__device__ __forceinline__ u32 cvtpk(float a, float b) {
  u32 r;
  asm("v_cvt_pk_bf16_f32 %0, %1, %2" : "=v"(r) : "v"(a), "v"(b));
  return r;
}

__device__ __forceinline__ f32x4 ldf4(const float* p) {
  float4 v = *(const float4*)p;
  f32x4 z = {v.x, v.y, v.z, v.w};
  return z;
}

// round-to-nearest-even fp32 -> bf16 (finite inputs only)
__device__ __forceinline__ u16 bf16_rne(float x) {
  unsigned u = __float_as_uint(x);
  u += 0x7FFFu + ((u >> 16) & 1u);
  return (u16)(u >> 16);
}
// split fp32 into bf16 hi + bf16 lo (x ~= hi + lo, ~16-bit mantissa total)
__device__ __forceinline__ void cvt_pair(float x, u16 &hi, u16 &lo) {
  hi = bf16_rne(x);
  lo = bf16_rne(x - __uint_as_float(((unsigned)hi) << 16));
}

// ------------------------------------------------------------------
// K0a: x [8192,256] f32 -> xh, xl bf16
// ------------------------------------------------------------------
__global__ void k_cvt_x(const float* __restrict__ x,
                        u16* __restrict__ xh, u16* __restrict__ xl) {
  int i = (blockIdx.x * 256 + threadIdx.x) * 4;
  float4 v = *(const float4*)(x + i);
  u16x4 h, l;
  u16 th, tl;
  cvt_pair(v.x, th, tl); h[0] = th; l[0] = tl;
  cvt_pair(v.y, th, tl); h[1] = th; l[1] = tl;
  cvt_pair(v.z, th, tl); h[2] = th; l[2] = tl;
  cvt_pair(v.w, th, tl); h[3] = th; l[3] = tl;
  *(u16x4*)(xh + i) = h;
  *(u16x4*)(xl + i) = l;
}

// ------------------------------------------------------------------
// K0b: weights -> transposed bf16 pairs via LDS tile transpose (coalesced).
// ------------------------------------------------------------------
__global__ void k_cvt_w(const float* __restrict__ Wq, const float* __restrict__ Wk,
                        const float* __restrict__ Wv, const float* __restrict__ Wg,
                        const float* __restrict__ Wo,
                        u16* __restrict__ wt4h, u16* __restrict__ wt4l,
                        u16* __restrict__ woth, u16* __restrict__ wotl) {
  __shared__ float tile[64][65];
  const int mat = blockIdx.x / 16, tt = blockIdx.x % 16;
  const int m0 = (tt >> 2) * 64, n0 = (tt & 3) * 64;
  const float* W = (mat == 0) ? Wq : (mat == 1) ? Wk : (mat == 2) ? Wv
                 : (mat == 3) ? Wg : Wo;
  const int tr = threadIdx.x >> 6;   // 0..3
  const int tc = threadIdx.x & 63;   // 0..63
#pragma unroll
  for (int i = 0; i < 16; ++i) {
    int row = i * 4 + tr;
    tile[row][tc] = W[(m0 + row) * 256 + n0 + tc];
  }
  __syncthreads();
  u16* dh = (mat < 4) ? wt4h : woth;
  u16* dl = (mat < 4) ? wt4l : wotl;
  const int nbase = (mat < 4) ? mat * 256 : 0;
#pragma unroll
  for (int i = 0; i < 16; ++i) {
    int row = i * 4 + tr;               // n-dim
    u16 hi, lo; cvt_pair(tile[tc][row], hi, lo);
    dh[(nbase + n0 + row) * 256 + m0 + tc] = hi;
    dl[(nbase + n0 + row) * 256 + m0 + tc] = lo;
  }
}

// ------------------------------------------------------------------
// Kernel A: fused QKVG projection GEMM.  y = x @ [Wq|Wk|Wv|Wg]
// ------------------------------------------------------------------
__global__ __launch_bounds__(256, 2) void k_proj(
    const u16* __restrict__ xh, const u16* __restrict__ xl,
    const u16* __restrict__ wt4h, const u16* __restrict__ wt4l,
    const float* __restrict__ bg,
    u16* __restrict__ qh, u16* __restrict__ ql,
    u16* __restrict__ kh, u16* __restrict__ kl,
    u16* __restrict__ vth, u16* __restrict__ vtl,
    float* __restrict__ g) {
  const int m0 = blockIdx.x * 128;      // 64 blocks
  const int n0 = blockIdx.y * 128;      // 8 blocks
  const int wave = threadIdx.x >> 6;
  const int lane = threadIdx.x & 63;
  const int wm = (wave >> 1) * 64, wn = (wave & 1) * 64;
  const int l15 = lane & 15, lg = lane >> 4;

  f32x4 acc[4][4] = {};
  for (int ks = 0; ks < 8; ++ks) {
    u16x8 a_h[4], a_l[4], b_h[4], b_l[4];
#pragma unroll
    for (int mt = 0; mt < 4; ++mt) {
      int base = (m0 + wm + mt * 16 + l15) * 256 + ks * 32 + lg * 8;
      a_h[mt] = *(const u16x8*)(xh + base);
      a_l[mt] = *(const u16x8*)(xl + base);
    }
#pragma unroll
    for (int nt = 0; nt < 4; ++nt) {
      int base = (n0 + wn + nt * 16 + l15) * 256 + ks * 32 + lg * 8;
      b_h[nt] = *(const u16x8*)(wt4h + base);
      b_l[nt] = *(const u16x8*)(wt4l + base);
    }
#pragma unroll
    for (int mt = 0; mt < 4; ++mt)
#pragma unroll
      for (int nt = 0; nt < 4; ++nt) {
        acc[mt][nt] = mfma16(a_h[mt], b_h[nt], acc[mt][nt]);
        acc[mt][nt] = mfma16(a_h[mt], b_l[nt], acc[mt][nt]);
        acc[mt][nt] = mfma16(a_l[mt], b_h[nt], acc[mt][nt]);
      }
  }

  const float qscale = 0.17677669529663687f;  // 1/sqrt(32)
#pragma unroll
  for (int mt = 0; mt < 4; ++mt)
#pragma unroll
    for (int nt = 0; nt < 4; ++nt) {
      const int rowb = m0 + wm + mt * 16 + lg * 4;  // + r (4 consecutive rows)
      const int col  = n0 + wn + nt * 16 + l15;
      const int bb = rowb >> 11, s = rowb & 2047;
      const int mid = col >> 8, d = col & 255;
      const int hh = d >> 5, c = d & 31;
      if (mid == 3) {
#pragma unroll
        for (int r = 0; r < 4; ++r) {
          float gv = 1.0f / (1.0f + __expf(-(acc[mt][nt][r] + bg[d])));
          g[(rowb + r) * 256 + d] = gv;
        }
      } else if (mid == 2) {
        u16x4 vh4, vl4;
#pragma unroll
        for (int r = 0; r < 4; ++r) {
          u16 th, tl; cvt_pair(acc[mt][nt][r], th, tl);
          vh4[r] = th; vl4[r] = tl;
        }
        size_t idx = ((size_t)(bb * HH + hh) * CC + c) * SS + s;
        *(u16x4*)(vth + idx) = vh4;
        *(u16x4*)(vtl + idx) = vl4;
      } else {
#pragma unroll
        for (int r = 0; r < 4; ++r) {
          float val = acc[mt][nt][r];
          if (mid == 0) val *= qscale;
          u16 th, tl; cvt_pair(val, th, tl);
          size_t idx = ((size_t)(bb * HH + hh) * SS + s + r) * CC + c;
          if (mid == 0) { qh[idx] = th; ql[idx] = tl; }
          else          { kh[idx] = th; kl[idx] = tl; }
        }
      }
    }
}

// ------------------------------------------------------------------
// Kernel B: attention, batch-pair bias sharing.
// Grid 512 = (h 8) x (js 2) x (bp 2) x (qc 16); 256 thr, 4 waves x 32 q.
// Block: 128 q-rows, j-extent 1024 (16 tiles), batches {2bp, 2bp+1}
// processed SERIALLY per j-tile (2 phases), re-using the bias C-init
// registers for both -> bias port-segments per CU halved (the measured
// common bottleneck of R7/R8/R13 at ~49K segs/CU).  Buffer parity is
// static (2 phases/tile): all state arrays statically indexed (rule #20).
// Primitives verbatim from R13 (P-LDS PV 16x16x32, bias prefetch, cvtpk).
// Writes unnormalized numer + denom per js-half; k_out combines (R8).
// ------------------------------------------------------------------
__global__ __launch_bounds__(256, 2) void k_attn(
    const u16* __restrict__ qh, const u16* __restrict__ ql,
    const u16* __restrict__ kh, const u16* __restrict__ kl,
    const u16* __restrict__ vth, const u16* __restrict__ vtl,
    const float* __restrict__ bias,
    float* __restrict__ n0, float* __restrict__ n1,
    float* __restrict__ d0, float* __restrict__ d1) {
  // u16 layout per KV buffer (10752 u16 = 21504 B):
  //   KH [64][40] @0, KL @2560, VH [32][88] @5120, VL @7936
  // buffers at u16 0 and 10752; P tiles (u32) at dword 10752:
  //   per wave 2304 u32 = 2 qt x (hi 576 + lo 576), stride-36 rows.
  __shared__ __align__(16) u32 lds32[19968];   // 79,872 B -> 2 blocks/CU
  u16* ldsu = (u16*)lds32;

  const int idx = blockIdx.x;            // 512
  const int h   = idx & 7;               // head -> XCD pinning
  const int js  = (idx >> 3) & 1;        // j-half
  const int bp  = (idx >> 4) & 1;        // batch pair
  const int q0  = (idx >> 5) * 128;      // 16 q-chunks
  const int w    = threadIdx.x >> 6;     // 0..3
  const int lane = threadIdx.x & 63;
  const int l15 = lane & 15, lg = lane >> 4;
  const int t = threadIdx.x;
  const int jbase = js * 1024;

  float* nbuf = js ? n1 : n0;
  float* dbuf = js ? d1 : d0;

  // cooperative stage addressing (256 threads, u16x8 = 16B each)
  const int kj = t >> 2, kc = (t & 3) * 8;   // K: [64 j][32 c]
  const int vc = t >> 3, vj = (t & 7) * 8;   // V: [32 c][64 j]
  size_t kb[2], vb[2];
#pragma unroll
  for (int b2 = 0; b2 < 2; ++b2) {
    const int bh2 = (bp * 2 + b2) * HH + h;
    kb[b2] = ((size_t)bh2 * SS + jbase + kj) * CC + kc;
    vb[b2] = ((size_t)bh2 * CC + vc) * SS + jbase + vj;
  }

  // Q fragments (B operand: col=q=l15, k=c), resident for both batches
  u16x8 qfh[2][2], qfl[2][2];
#pragma unroll
  for (int b2 = 0; b2 < 2; ++b2)
#pragma unroll
    for (int qt = 0; qt < 2; ++qt) {
      int base = (((bp * 2 + b2) * HH + h) * SS + q0 + w * 32 + qt * 16 + l15)
                 * CC + lg * 8;
      qfh[b2][qt] = *(const u16x8*)(qh + base);
      qfl[b2][qt] = *(const u16x8*)(ql + base);
    }

  const float* biasQ[2];
#pragma unroll
  for (int qt = 0; qt < 2; ++qt)
    biasQ[qt] = bias + (size_t)h * SS * SS
              + (size_t)(q0 + w * 32 + qt * 16 + l15) * SS + jbase + lg * 4;

  u32* pw = lds32 + 10752 + w * 2304;   // per-wave P base (u32)

  f32x4 oacc[2][2][2] = {};   // [b2][qt][ct]
  float rs[2][2] = {};        // [b2][qt]

  // ---- prologue: stage (jt=0, b2=0) into buf0 + bias tile 0 ----
  f32x4 bcur[2][4];
  {
    u16x8 a = *(const u16x8*)(kh + kb[0]);
    u16x8 c = *(const u16x8*)(kl + kb[0]);
    u16x8 e = *(const u16x8*)(vth + vb[0]);
    u16x8 f = *(const u16x8*)(vtl + vb[0]);
#pragma unroll
    for (int qt = 0; qt < 2; ++qt)
#pragma unroll
      for (int at = 0; at < 4; ++at)
        bcur[qt][at] = ldf4(biasQ[qt] + at * 16);
    *(u16x8*)(ldsu + kj * 40 + kc) = a;
    *(u16x8*)(ldsu + 2560 + kj * 40 + kc) = c;
    *(u16x8*)(ldsu + 5120 + vc * 88 + vj) = e;
    *(u16x8*)(ldsu + 7936 + vc * 88 + vj) = f;
  }
  __syncthreads();

#pragma unroll 1
  for (int jt = 0; jt < 16; ++jt) {
#pragma unroll
    for (int b2 = 0; b2 < 2; ++b2) {
      const u16* lk = ldsu + b2 * 10752;        // static buffer parity
      u16* ln = ldsu + (b2 ^ 1) * 10752;
      const bool hasNext = (b2 == 0) || (jt < 15);
      const int njt = (b2 == 0) ? jt : jt + 1;  // next phase's j-tile
      const int nb2 = b2 ^ 1;

      // --- issue next phase's K/V global loads (hidden under compute) ---
      u16x8 skh, skl, svh, svl;
      if (hasNext) {
        size_t gk = kb[nb2] + (size_t)njt * 64 * CC;
        size_t gv = vb[nb2] + (size_t)njt * 64;
        skh = *(const u16x8*)(kh + gk);
        skl = *(const u16x8*)(kl + gk);
        svh = *(const u16x8*)(vth + gv);
        svl = *(const u16x8*)(vtl + gv);
      }
      // --- bias prefetch for next j-tile (during second phase) ---
      f32x4 bnxt[2][4];
      if (b2 == 1 && jt < 15) {
#pragma unroll
        for (int qt = 0; qt < 2; ++qt)
#pragma unroll
          for (int at = 0; at < 4; ++at)
            bnxt[qt][at] = ldf4(biasQ[qt] + (jt + 1) * 64 + at * 16);
      }

      // --- K fragments from LDS ---
      u16x8 ka_h[4], ka_l[4];
#pragma unroll
      for (int at = 0; at < 4; ++at) {
        int base = (at * 16 + l15) * 40 + lg * 8;
        ka_h[at] = *(const u16x8*)(lk + base);
        ka_l[at] = *(const u16x8*)(lk + 2560 + base);
      }
      // --- swapped QK^T, shared bias as C-init: D[j][q] ---
      f32x4 sacc[2][4];
#pragma unroll
      for (int qt = 0; qt < 2; ++qt)
#pragma unroll
        for (int at = 0; at < 4; ++at)
          sacc[qt][at] = bcur[qt][at];
#pragma unroll
      for (int at = 0; at < 4; ++at)
#pragma unroll
        for (int qt = 0; qt < 2; ++qt) {
          sacc[qt][at] = mfma16(ka_h[at], qfh[b2][qt], sacc[qt][at]);
          sacc[qt][at] = mfma16(ka_h[at], qfl[b2][qt], sacc[qt][at]);
          sacc[qt][at] = mfma16(ka_l[at], qfh[b2][qt], sacc[qt][at]);
        }
      // --- exp + rowsum + cvt_pk pack + P LDS write ---
#pragma unroll
      for (int qt = 0; qt < 2; ++qt) {
        u32* pq = pw + qt * 1152;
#pragma unroll
        for (int at = 0; at < 4; ++at) {
          float p0 = __expf(sacc[qt][at][0]);
          float p1 = __expf(sacc[qt][at][1]);
          float p2 = __expf(sacc[qt][at][2]);
          float p3 = __expf(sacc[qt][at][3]);
          rs[b2][qt] += (p0 + p1) + (p2 + p3);
          u32 hA = cvtpk(p0, p1), hB = cvtpk(p2, p3);
          float f0 = __uint_as_float(hA << 16);
          float f1 = __uint_as_float(hA & 0xffff0000u);
          float f2 = __uint_as_float(hB << 16);
          float f3 = __uint_as_float(hB & 0xffff0000u);
          u32 lA = cvtpk(p0 - f0, p1 - f1);
          u32 lB = cvtpk(p2 - f2, p3 - f3);
          int off = l15 * 36 + 8 * at + 2 * lg;
          uint2 Hv; Hv.x = hA; Hv.y = hB;
          uint2 Lv; Lv.x = lA; Lv.y = lB;
          *(uint2*)&pq[off] = Hv;
          *(uint2*)&pq[off + 576] = Lv;
        }
      }
      // --- PV: A = P (row=q=l15, k=j), B = V[c][j] from LDS ---
#pragma unroll
      for (int ks = 0; ks < 2; ++ks) {
        int roff = l15 * 36 + 16 * ks + 4 * lg;
        u16x8 pa_h[2], pa_l[2];
#pragma unroll
        for (int qt = 0; qt < 2; ++qt) {
          pa_h[qt] = *(const u16x8*)(pw + qt * 1152 + roff);
          pa_l[qt] = *(const u16x8*)(pw + qt * 1152 + 576 + roff);
        }
#pragma unroll
        for (int ct = 0; ct < 2; ++ct) {
          int voff = (ct * 16 + l15) * 88 + ks * 32 + lg * 8;
          u16x8 vfh = *(const u16x8*)(lk + 5120 + voff);
          u16x8 vfl = *(const u16x8*)(lk + 7936 + voff);
#pragma unroll
          for (int qt = 0; qt < 2; ++qt) {
            oacc[b2][qt][ct] = mfma16(pa_h[qt], vfh, oacc[b2][qt][ct]);
            oacc[b2][qt][ct] = mfma16(pa_h[qt], vfl, oacc[b2][qt][ct]);
            oacc[b2][qt][ct] = mfma16(pa_l[qt], vfh, oacc[b2][qt][ct]);
          }
        }
      }
      // --- write staged K/V into the other buffer; rotate bias regs ---
      if (hasNext) {
        *(u16x8*)(ln + kj * 40 + kc) = skh;
        *(u16x8*)(ln + 2560 + kj * 40 + kc) = skl;
        *(u16x8*)(ln + 5120 + vc * 88 + vj) = svh;
        *(u16x8*)(ln + 7936 + vc * 88 + vj) = svl;
      }
      if (b2 == 1 && jt < 15) {
#pragma unroll
        for (int qt = 0; qt < 2; ++qt)
#pragma unroll
          for (int at = 0; at < 4; ++at)
            bcur[qt][at] = bnxt[qt][at];
      }
      __syncthreads();
    }
  }

  // epilogue: rowsums + unnormalized numer/denom (R8 scheme)
#pragma unroll
  for (int b2 = 0; b2 < 2; ++b2) {
    const int bfull = bp * 2 + b2;
#pragma unroll
    for (int qt = 0; qt < 2; ++qt) {
      rs[b2][qt] += __shfl_xor(rs[b2][qt], 16, 64);
      rs[b2][qt] += __shfl_xor(rs[b2][qt], 32, 64);
      if (lg == 0)
        dbuf[(size_t)(bfull * SS + q0 + w * 32 + qt * 16 + l15) * HH + h] =
            rs[b2][qt];
#pragma unroll
      for (int ct = 0; ct < 2; ++ct)
#pragma unroll
        for (int r = 0; r < 4; ++r) {
          int qg = q0 + w * 32 + qt * 16 + lg * 4 + r;
          nbuf[((size_t)(bfull * SS + qg) * HH + h) * CC + ct * 16 + l15] =
              oacc[b2][qt][ct][r];
        }
    }
  }
}

// ------------------------------------------------------------------
// Kernel C: out = (g .* (n0+n1)/(d0+d1)) @ Wo + bo.  M=8192, N=256, K=256.
// ------------------------------------------------------------------
__global__ __launch_bounds__(256, 2) void k_out(
    const float* __restrict__ n0, const float* __restrict__ n1,
    const float* __restrict__ d0, const float* __restrict__ d1,
    const float* __restrict__ g,
    const u16* __restrict__ woth, const u16* __restrict__ wotl,
    const float* __restrict__ bo, float* __restrict__ out) {
  const int m0 = blockIdx.x * 32;    // 256 blocks
  const int nn0 = blockIdx.y * 128;  // 2 blocks
  const int wave = threadIdx.x >> 6;
  const int lane = threadIdx.x & 63;
  const int wn = wave * 32;
  const int l15 = lane & 15, lg = lane >> 4;

  f32x4 acc[2][2] = {};
  for (int ks = 0; ks < 8; ++ks) {
    u16x8 a_h[2], a_l[2], b_h[2], b_l[2];
#pragma unroll
    for (int mt = 0; mt < 2; ++mt) {
      int row = m0 + mt * 16 + l15;
      int base = row * 256 + ks * 32 + lg * 8;
      float inv = 1.0f / (d0[row * 8 + ks] + d1[row * 8 + ks]);
      float4 a0 = *(const float4*)(n0 + base);
      float4 a1 = *(const float4*)(n0 + base + 4);
      float4 c0 = *(const float4*)(n1 + base);
      float4 c1 = *(const float4*)(n1 + base + 4);
      float4 g0 = *(const float4*)(g + base);
      float4 g1 = *(const float4*)(g + base + 4);
      float pr[8] = {(a0.x + c0.x) * inv * g0.x, (a0.y + c0.y) * inv * g0.y,
                     (a0.z + c0.z) * inv * g0.z, (a0.w + c0.w) * inv * g0.w,
                     (a1.x + c1.x) * inv * g1.x, (a1.y + c1.y) * inv * g1.y,
                     (a1.z + c1.z) * inv * g1.z, (a1.w + c1.w) * inv * g1.w};
      union { u16 s[8]; u16x8 v; } uh, ul;
#pragma unroll
      for (int e = 0; e < 8; ++e) { u16 th, tl; cvt_pair(pr[e], th, tl); uh.s[e] = th; ul.s[e] = tl; }
      a_h[mt] = uh.v; a_l[mt] = ul.v;
    }
#pragma unroll
    for (int nt = 0; nt < 2; ++nt) {
      int base = (nn0 + wn + nt * 16 + l15) * 256 + ks * 32 + lg * 8;
      b_h[nt] = *(const u16x8*)(woth + base);
      b_l[nt] = *(const u16x8*)(wotl + base);
    }
#pragma unroll
    for (int mt = 0; mt < 2; ++mt)
#pragma unroll
      for (int nt = 0; nt < 2; ++nt) {
        acc[mt][nt] = mfma16(a_h[mt], b_h[nt], acc[mt][nt]);
        acc[mt][nt] = mfma16(a_h[mt], b_l[nt], acc[mt][nt]);
        acc[mt][nt] = mfma16(a_l[mt], b_h[nt], acc[mt][nt]);
      }
  }
#pragma unroll
  for (int mt = 0; mt < 2; ++mt)
#pragma unroll
    for (int nt = 0; nt < 2; ++nt)
#pragma unroll
      for (int r = 0; r < 4; ++r) {
        int row = m0 + mt * 16 + lg * 4 + r;
        int col = nn0 + wn + nt * 16 + l15;
        out[row * 256 + col] = acc[mt][nt][r] + bo[col];
      }
}

// ------------------------------------------------------------------
extern "C" void kernel_launch(void* const* d_in, const int* in_sizes, int n_in,
                              void* d_out, int out_size, void* d_ws, size_t ws_size,
                              hipStream_t stream) {
  const float* x    = (const float*)d_in[0];
  const float* bias = (const float*)d_in[1];
  const float* Wq   = (const float*)d_in[2];
  const float* Wk   = (const float*)d_in[3];
  const float* Wv   = (const float*)d_in[4];
  const float* Wg   = (const float*)d_in[5];
  const float* bg   = (const float*)d_in[6];
  const float* Wo   = (const float*)d_in[7];
  const float* bo   = (const float*)d_in[8];
  float* out = (float*)d_out;

  char* p = (char*)d_ws;
  size_t used = 0;
  auto alloc = [&](size_t bytes) -> void* {
    void* r = p + used;
    used += (bytes + 255) & ~(size_t)255;
    return r;
  };
  const size_t NTOK = (size_t)BB * SS * CIN;   // 2,097,152
  u16* xh   = (u16*)alloc(NTOK * 2);
  u16* xl   = (u16*)alloc(NTOK * 2);
  u16* wt4h = (u16*)alloc(1024 * 256 * 2);
  u16* wt4l = (u16*)alloc(1024 * 256 * 2);
  u16* woth = (u16*)alloc(256 * 256 * 2);
  u16* wotl = (u16*)alloc(256 * 256 * 2);
  u16* qh   = (u16*)alloc(NTOK * 2);
  u16* ql   = (u16*)alloc(NTOK * 2);
  u16* kh   = (u16*)alloc(NTOK * 2);
  u16* kl   = (u16*)alloc(NTOK * 2);
  u16* vth  = (u16*)alloc(NTOK * 2);
  u16* vtl  = (u16*)alloc(NTOK * 2);
  float* gbuf = (float*)alloc(NTOK * 4);
  float* nb0  = (float*)alloc(NTOK * 4);
  float* nb1  = (float*)alloc(NTOK * 4);
  float* db0  = (float*)alloc((size_t)BB * SS * HH * 4);
  float* db1  = (float*)alloc((size_t)BB * SS * HH * 4);
  if (used > ws_size) return;

  k_cvt_x<<<dim3(2048), dim3(256), 0, stream>>>(x, xh, xl);
  k_cvt_w<<<dim3(80), dim3(256), 0, stream>>>(Wq, Wk, Wv, Wg, Wo, wt4h, wt4l, woth, wotl);
  k_proj<<<dim3(64, 8), dim3(256), 0, stream>>>(xh, xl, wt4h, wt4l, bg,
                                                qh, ql, kh, kl, vth, vtl, gbuf);
  k_attn<<<dim3(512), dim3(256), 0, stream>>>(qh, ql, kh, kl, vth, vtl, bias,
                                              nb0, nb1, db0, db1);
  k_out<<<dim3(256, 2), dim3(256), 0, stream>>>(nb0, nb1, db0, db1, gbuf,
                                                woth, wotl, bo, out);
}